// Round 12
// baseline (300.265 us; speedup 1.0000x reference)
//
#include <hip/hip_runtime.h>
#include <math.h>

#define BB 8
#define PP 10
#define SS 160
#define FXD 11
#define DD 64
#define DFF 256
#define NROW (BB*PP*SS)   /* 12800 */
#define NBP  (BB*PP)      /* 80 */

// d_out layout (floats): pred | pred_resampl | K | V | R | attn
#define OFF_PRED  0
#define OFF_PREDR 12800
#define OFF_K     25600
#define OFF_V     844800
#define OFF_R     1664000
#define OFF_ATTN  2483200

#define MAGIC 0x1357BDFu

typedef short short8 __attribute__((ext_vector_type(8)));
typedef float f32x4  __attribute__((ext_vector_type(4)));

__device__ __forceinline__ void fma4(float4& acc, float s, const float4& b){
  acc.x += s*b.x; acc.y += s*b.y; acc.z += s*b.z; acc.w += s*b.w;
}
template<int N>
__device__ __forceinline__ void wred_sum_n(float (&v)[N]){
#pragma unroll
  for (int m = 32; m >= 1; m >>= 1){
#pragma unroll
    for (int i = 0; i < N; ++i) v[i] += __shfl_xor(v[i], m, 64);
  }
}
template<int N>
__device__ __forceinline__ void qred_sum_n(float (&v)[N]){
#pragma unroll
  for (int m = 8; m >= 1; m >>= 1){
#pragma unroll
    for (int i = 0; i < N; ++i) v[i] += __shfl_xor(v[i], m, 64);
  }
}
template<int N>
__device__ __forceinline__ void qred_max_n(float (&v)[N]){
#pragma unroll
  for (int m = 8; m >= 1; m >>= 1){
#pragma unroll
    for (int i = 0; i < N; ++i) v[i] = fmaxf(v[i], __shfl_xor(v[i], m, 64));
  }
}
// bf16 pack (RTN-even)
__device__ __forceinline__ unsigned f2bf(float f){
  unsigned u = __float_as_uint(f);
  return (u + 0x7fffu + ((u >> 16) & 1u)) >> 16;
}
__device__ __forceinline__ unsigned packbf2(float x, float y){
  return f2bf(x) | (f2bf(y) << 16);
}
__device__ __forceinline__ f32x4 mfma16(uint4 a, uint4 b, f32x4 c){
  union { uint4 u; short8 s; } ua, ub;
  ua.u = a; ub.u = b;
  return __builtin_amdgcn_mfma_f32_16x16x32_bf16(ua.s, ub.s, c, 0, 0, 0);
}
__device__ __forceinline__ uint4 pack8(float4 a, float4 b){
  uint4 r;
  r.x = packbf2(a.x, a.y); r.y = packbf2(a.z, a.w);
  r.z = packbf2(b.x, b.y); r.w = packbf2(b.z, b.w);
  return r;
}

// ---------------------------------------------------------------------------
// Single fused kernel, grid (80 bp, 10 c), 256 thr, 4 blocks/CU guaranteed
// (VGPR<=128 via launch_bounds, LDS 30.6KB) -> all 800 blocks co-resident.
// Block (bp,c): [produce] proj+QKV for its own 16 rows (Q -> LDS only; K/V ->
// d_out fp32 + packed ws) -> release flag. [consume] spin-acquire flags of
// producers 0..c-1, fence, then attention chunk + FFN + LNs + pred, all MFMA.
// ---------------------------------------------------------------------------
__global__ __launch_bounds__(256, 4) void k_all(
    const float* __restrict__ inp,
    const float* __restrict__ Wp, const float* __restrict__ bpj,
    const float* __restrict__ Wq, const float* __restrict__ bq,
    const float* __restrict__ Wk, const float* __restrict__ bk,
    const float* __restrict__ Wv, const float* __restrict__ bv,
    const float* __restrict__ Wo, const float* __restrict__ bo,
    const float* __restrict__ g1, const float* __restrict__ b1l,
    const float* __restrict__ W1, const float* __restrict__ b1,
    const float* __restrict__ W2, const float* __restrict__ b2,
    const float* __restrict__ g2, const float* __restrict__ b2l,
    const float* __restrict__ Wf, const float* __restrict__ bf,
    unsigned* __restrict__ Kp, unsigned* __restrict__ Vp,
    unsigned* __restrict__ flags,
    float* __restrict__ Kc, float* __restrict__ Vc,
    float* __restrict__ attn, float* __restrict__ R,
    float* __restrict__ pred, float* __restrict__ predr){
  // LDS arenas (unions by lifetime):
  __shared__ __align__(16) unsigned char smA[5376];   // ps2 (A->B) -> zos (C->LN1)
  unsigned* ps2 = (unsigned*)smA;                     // 16 x 84 u32
  float*    zos = (float*)smA;                        // 16 x 68 f
  __shared__ float mws[80], sws[80];
  __shared__ __align__(16) float zs[16*68];           // Z (B->C)
  __shared__ __align__(16) float os[16*68];           // LN1 out (residual)
  __shared__ __align__(16) unsigned osxs2[16*36];     // xs2 (producer) -> os2 (LN1->FFN1)
  __shared__ __align__(16) unsigned asqp[16*132];     // qp2 (producer->A) -> as2 (FFN1->FFN2)
  __shared__ __align__(16) float xlnb[16*68];         // x tile (producer->C) -> lnb (FFN2->LN2)
  __shared__ __align__(16) float ins[16*12];
  unsigned* qp2 = asqp;                               // first 512 u32

  int tid = threadIdx.x;
  int bp = blockIdx.x, c = blockIdx.y;
  int t0 = c*16;
  int g  = bp*10 + c;
  int row0 = g*16;
  int lane = tid & 63, w = tid >> 6, nl = lane & 15, q = lane >> 4;
  float* Ab = attn + bp*(SS*SS);

  // ---- early zero-fills (overlap producer work) ----
  {
    int zc0 = (c+1)*16, zcw = 160 - zc0;
    if (zcw > 0){
      int perrow = zcw >> 2;
      int nq = 16*perrow;
      for (int i = tid; i < nq; i += 256){
        int r = i / perrow, col = zc0 + (i - r*perrow)*4;
        *(float4*)&Ab[(t0 + r)*SS + col] = make_float4(0.f,0.f,0.f,0.f);
      }
    }
    if (!(c & 1) && tid < 128){
      int r = tid >> 3, j = tid & 7;
      ps2[r*84 + (c+1)*8 + j] = 0;
    }
  }
  // ---- stage own inputs ----
  for (int i = tid; i < 16*FXD; i += 256){
    int r = i / FXD, f = i - r*FXD;
    ins[r*12 + f] = inp[row0*FXD + i];
  }
  __syncthreads();

  // ---- proj: x = (inp@Wp+bp)*8 -> xlnb (fp32) + osxs2 (bf16 packed) ----
  {
    int tc = tid & 15, tr = tid >> 4;
    float4 a = make_float4(0.f,0.f,0.f,0.f);
#pragma unroll
    for (int f = 0; f < FXD; ++f){
      float v = ins[tr*12 + f];
      float4 w4 = *(const float4*)&Wp[f*64 + tc*4];
      fma4(a, v, w4);
    }
    float4 bp4 = *(const float4*)&bpj[tc*4];
    float4 xv = make_float4((a.x+bp4.x)*8.f, (a.y+bp4.y)*8.f,
                            (a.z+bp4.z)*8.f, (a.w+bp4.w)*8.f);
    *(float4*)&xlnb[tr*68 + tc*4] = xv;
    osxs2[tr*36 + tc*2]     = packbf2(xv.x, xv.y);
    osxs2[tr*36 + tc*2 + 1] = packbf2(xv.z, xv.w);
  }
  __syncthreads();

  // ---- QKV via MFMA (weight B-frags in-register from global fp32) ----
  {
    uint4 a0 = *(const uint4*)&osxs2[nl*36 + q*4];
    uint4 a1 = *(const uint4*)&osxs2[nl*36 + 16 + q*4];
    int n = w*16 + nl;
    bool evenlane = !(lane & 1);
    const float* Wm[3] = {Wq, Wk, Wv};
    const float* bias[3] = {bq, bk, bv};
#pragma unroll
    for (int mat = 0; mat < 3; ++mat){
      const float* W = Wm[mat];
      float w0 = W[(q*8+0)*64+n], w1 = W[(q*8+1)*64+n];
      float w2 = W[(q*8+2)*64+n], w3 = W[(q*8+3)*64+n];
      float w4 = W[(q*8+4)*64+n], w5 = W[(q*8+5)*64+n];
      float w6 = W[(q*8+6)*64+n], w7 = W[(q*8+7)*64+n];
      uint4 b0; b0.x = packbf2(w0,w1); b0.y = packbf2(w2,w3);
      b0.z = packbf2(w4,w5); b0.w = packbf2(w6,w7);
      float v0 = W[(32+q*8+0)*64+n], v1 = W[(32+q*8+1)*64+n];
      float v2 = W[(32+q*8+2)*64+n], v3 = W[(32+q*8+3)*64+n];
      float v4 = W[(32+q*8+4)*64+n], v5 = W[(32+q*8+5)*64+n];
      float v6 = W[(32+q*8+6)*64+n], v7 = W[(32+q*8+7)*64+n];
      uint4 b1; b1.x = packbf2(v0,v1); b1.y = packbf2(v2,v3);
      b1.z = packbf2(v4,v5); b1.w = packbf2(v6,v7);
      f32x4 acc = {0.f,0.f,0.f,0.f};
      acc = mfma16(a0, b0, acc);
      acc = mfma16(a1, b1, acc);
      float bvv = bias[mat][n];
      float o[4];
#pragma unroll
      for (int r = 0; r < 4; ++r) o[r] = acc[r] + bvv;
      if (mat == 0){
        // Q -> LDS only (A-frag layout, packed along d)
#pragma unroll
        for (int r = 0; r < 4; ++r){
          float on = __shfl_xor(o[r], 1, 64);
          if (evenlane) qp2[(q*4+r)*32 + (n >> 1)] = packbf2(o[r], on);
        }
      } else if (mat == 1){
#pragma unroll
        for (int r = 0; r < 4; ++r){
          Kc[(row0 + q*4 + r)*64 + n] = o[r];
          float on = __shfl_xor(o[r], 1, 64);
          if (evenlane) Kp[(row0 + q*4 + r)*32 + (n >> 1)] = packbf2(o[r], on);
        }
      } else {
#pragma unroll
        for (int r = 0; r < 4; ++r)
          Vc[(row0 + q*4 + r)*64 + n] = o[r];
        unsigned* vd = &Vp[bp*(64*80) + n*80 + c*8 + q*2];
        vd[0] = packbf2(o[0], o[1]);
        vd[1] = packbf2(o[2], o[3]);
      }
    }
  }
  __threadfence();
  __syncthreads();                 // all K/V stores drained block-wide
  if (tid == 0)
    __hip_atomic_store(&flags[g], MAGIC, __ATOMIC_RELEASE,
                       __HIP_MEMORY_SCOPE_AGENT);

  // ---- prefetch Wo B-frags while producers finish ----
  uint4 wofrag[2];
  {
    int n = w*16 + nl;
#pragma unroll
    for (int ks = 0; ks < 2; ++ks){
      int kb = ks*32 + q*8;
      wofrag[ks].x = packbf2(Wo[(kb+0)*64+n], Wo[(kb+1)*64+n]);
      wofrag[ks].y = packbf2(Wo[(kb+2)*64+n], Wo[(kb+3)*64+n]);
      wofrag[ks].z = packbf2(Wo[(kb+4)*64+n], Wo[(kb+5)*64+n]);
      wofrag[ks].w = packbf2(Wo[(kb+6)*64+n], Wo[(kb+7)*64+n]);
    }
  }

  // ---- wait for producers 0..c-1 of this bp ----
  if (tid < c){
    while (__hip_atomic_load(&flags[bp*10 + tid], __ATOMIC_ACQUIRE,
                             __HIP_MEMORY_SCOPE_AGENT) != MAGIC)
      __builtin_amdgcn_s_sleep(2);
  }
  __syncthreads();
  __threadfence();                 // acquire side: invalidate L1 for Kp/Vp reads

  // ---- phase A: logits via MFMA over live tiles ----
  int ntiles = (w <= c) ? (((c - w) >> 2) + 1) : 0;
  {
    const unsigned* qpr = &qp2[nl*32];
    uint4 aq0 = *(const uint4*)&qpr[q*4];
    uint4 aq1 = *(const uint4*)&qpr[16 + q*4];
    float lg[3][4], ev[3][4];
    f32x4 pacc[3];
#pragma unroll
    for (int i = 0; i < 3; ++i){
      pacc[i] = (f32x4){0.f,0.f,0.f,0.f};
      if (i < ntiles){
        const unsigned* kpr = &Kp[(bp*SS + (w+4*i)*16 + nl)*32];
        uint4 b0 = *(const uint4*)&kpr[q*4];
        uint4 b1 = *(const uint4*)&kpr[16 + q*4];
        pacc[i] = mfma16(aq0, b0, pacc[i]);
        pacc[i] = mfma16(aq1, b1, pacc[i]);
      }
    }
    float mw_[4];
#pragma unroll
    for (int r = 0; r < 4; ++r){
      int t = t0 + q*4 + r;
      float m_ = -1e30f;
#pragma unroll
      for (int i = 0; i < 3; ++i){
        if (i < ntiles){
          int s = (w + 4*i)*16 + nl;
          float l = (s <= t) ? pacc[i][r]*0.125f : -1e30f;
          lg[i][r] = l; m_ = fmaxf(m_, l);
        }
      }
      mw_[r] = m_;
    }
    qred_max_n<4>(mw_);
    float sw_[4];
#pragma unroll
    for (int r = 0; r < 4; ++r){
      float s_ = 0.f;
#pragma unroll
      for (int i = 0; i < 3; ++i){
        if (i < ntiles){
          float e = __expf(lg[i][r] - mw_[r]);
          ev[i][r] = e; s_ += e;
        }
      }
      sw_[r] = s_;
    }
    qred_sum_n<4>(sw_);
    if (nl == 0){
#pragma unroll
      for (int r = 0; r < 4; ++r){
        mws[(q*4+r)*5 + w] = mw_[r];
        sws[(q*4+r)*5 + w] = sw_[r];
      }
    }
    __syncthreads();
    float scale[4];
#pragma unroll
    for (int r = 0; r < 4; ++r){
      int row = q*4 + r;
      float m0 = mws[row*5+0], m1 = mws[row*5+1];
      float m2 = mws[row*5+2], m3 = mws[row*5+3];
      float gm = fmaxf(fmaxf(m0,m1), fmaxf(m2,m3));
      float tot = sws[row*5+0]*__expf(m0-gm) + sws[row*5+1]*__expf(m1-gm)
                + sws[row*5+2]*__expf(m2-gm) + sws[row*5+3]*__expf(m3-gm);
      scale[r] = __expf(mw_[r]-gm) / tot;
    }
#pragma unroll
    for (int i = 0; i < 3; ++i){
      if (i < ntiles){
        int s = (w + 4*i)*16 + nl;
#pragma unroll
        for (int r = 0; r < 4; ++r){
          float p_ = ev[i][r] * scale[r];
          Ab[(t0 + q*4 + r)*SS + s] = p_;
          float pn = __shfl_xor(p_, 1, 64);
          if (!(nl & 1))
            ps2[(q*4+r)*84 + (w+4*i)*8 + (nl >> 1)] = packbf2(p_, pn);
        }
      }
    }
  }
  __syncthreads();

  // ---- phase B: Z = P @ V over live K-range ----
  {
    int nks = (c + 2) >> 1;
    int d = w*16 + nl;
    const unsigned* vpd = &Vp[bp*(64*80) + d*80];
    f32x4 zacc = {0.f,0.f,0.f,0.f};
#pragma unroll
    for (int ks = 0; ks < 5; ++ks){
      if (ks < nks){
        uint4 bv = *(const uint4*)&vpd[ks*16 + q*4];
        uint4 ap = *(const uint4*)&ps2[nl*84 + ks*16 + q*4];
        zacc = mfma16(ap, bv, zacc);
      }
    }
#pragma unroll
    for (int r = 0; r < 4; ++r)
      zs[(q*4+r)*68 + d] = zacc[r];
  }
  __syncthreads();

  // ---- phase C: zo = Z@Wo + bo + x (x from LDS) ----
  {
    f32x4 cacc = {0.f,0.f,0.f,0.f};
#pragma unroll
    for (int ks = 0; ks < 2; ++ks){
      float4 f0 = *(const float4*)&zs[nl*68 + ks*32 + q*8];
      float4 f1 = *(const float4*)&zs[nl*68 + ks*32 + q*8 + 4];
      uint4 a = pack8(f0, f1);
      cacc = mfma16(a, wofrag[ks], cacc);
    }
    int col = w*16 + nl;
    float bov = bo[col];
#pragma unroll
    for (int r = 0; r < 4; ++r){
      int row = q*4 + r;
      zos[row*68 + col] = cacc[r] + bov + xlnb[row*68 + col];
    }
  }
  __syncthreads();

  // ---- LN1 -> os (fp32) + os2 (packed bf16) ----
  {
    float h[4], s8v[8];
#pragma unroll
    for (int j = 0; j < 4; ++j){
      int r = w + 4*j;
      h[j] = zos[r*68 + lane];
      s8v[j] = h[j]; s8v[4+j] = h[j]*h[j];
    }
    wred_sum_n<8>(s8v);
    float gl = g1[lane], bl = b1l[lane];
#pragma unroll
    for (int j = 0; j < 4; ++j){
      int r = w + 4*j;
      float mu = s8v[j]*(1.f/64.f);
      float var = s8v[4+j]*(1.f/64.f) - mu*mu;
      float o = gl*(h[j]-mu)*rsqrtf(fmaxf(var,0.f) + 1e-6f) + bl;
      os[r*68 + lane] = o;
      float on = __shfl_xor(o, 1, 64);
      if (!(lane & 1)) osxs2[r*36 + (lane >> 1)] = packbf2(o, on);
    }
  }
  __syncthreads();

  // ---- FFN1: a = relu(os@W1+b1); W1 frags packed in-register (L1-hot) ----
  {
    uint4 ao0 = *(const uint4*)&osxs2[nl*36 + q*4];
    uint4 ao1 = *(const uint4*)&osxs2[nl*36 + 16 + q*4];
    f32x4 fa[4];
#pragma unroll
    for (int i = 0; i < 4; ++i){
      int n = (w*4+i)*16 + nl;
      uint4 b0, b1v;
      b0.x = packbf2(W1[(q*8+0)*256+n], W1[(q*8+1)*256+n]);
      b0.y = packbf2(W1[(q*8+2)*256+n], W1[(q*8+3)*256+n]);
      b0.z = packbf2(W1[(q*8+4)*256+n], W1[(q*8+5)*256+n]);
      b0.w = packbf2(W1[(q*8+6)*256+n], W1[(q*8+7)*256+n]);
      b1v.x = packbf2(W1[(32+q*8+0)*256+n], W1[(32+q*8+1)*256+n]);
      b1v.y = packbf2(W1[(32+q*8+2)*256+n], W1[(32+q*8+3)*256+n]);
      b1v.z = packbf2(W1[(32+q*8+4)*256+n], W1[(32+q*8+5)*256+n]);
      b1v.w = packbf2(W1[(32+q*8+6)*256+n], W1[(32+q*8+7)*256+n]);
      fa[i] = (f32x4){0.f,0.f,0.f,0.f};
      fa[i] = mfma16(ao0, b0, fa[i]);
      fa[i] = mfma16(ao1, b1v, fa[i]);
    }
#pragma unroll
    for (int i = 0; i < 4; ++i){
      int n = (w*4+i)*16 + nl;
      float b1b = b1[n];
#pragma unroll
      for (int r = 0; r < 4; ++r){
        float a_ = fmaxf(fa[i][r] + b1b, 0.f);
        float an = __shfl_xor(a_, 1, 64);
        if (!(nl & 1))
          asqp[(q*4+r)*132 + w*32 + i*8 + (nl >> 1)] = packbf2(a_, an);
      }
    }
  }
  __syncthreads();

  // ---- FFN2: r0 = a@W2 + b2 + os; W2 frags in-register ----
  {
    int n2 = w*16 + nl;
    f32x4 f2 = {0.f,0.f,0.f,0.f};
#pragma unroll
    for (int ks = 0; ks < 8; ++ks){
      int kb = ks*32 + q*8;
      uint4 b;
      b.x = packbf2(W2[(kb+0)*64+n2], W2[(kb+1)*64+n2]);
      b.y = packbf2(W2[(kb+2)*64+n2], W2[(kb+3)*64+n2]);
      b.z = packbf2(W2[(kb+4)*64+n2], W2[(kb+5)*64+n2]);
      b.w = packbf2(W2[(kb+6)*64+n2], W2[(kb+7)*64+n2]);
      uint4 a = *(const uint4*)&asqp[nl*132 + ks*16 + q*4];
      f2 = mfma16(a, b, f2);
    }
    float b2v = b2[n2];
#pragma unroll
    for (int r = 0; r < 4; ++r){
      int row = q*4 + r;
      xlnb[row*68 + n2] = f2[r] + b2v + os[row*68 + n2];
    }
  }
  __syncthreads();

  // ---- LN2 -> R, pred ----
  {
    float wfv = Wf[lane], bfv = bf[0];
    float h[4], s8v[8];
#pragma unroll
    for (int j = 0; j < 4; ++j){
      int r = w*4 + j;
      h[j] = xlnb[r*68 + lane];
      s8v[j] = h[j]; s8v[4+j] = h[j]*h[j];
    }
    wred_sum_n<8>(s8v);
    float g2l = g2[lane], b2ll = b2l[lane];
    float pr[4];
#pragma unroll
    for (int j = 0; j < 4; ++j){
      int r = w*4 + j;
      float mu = s8v[j]*(1.f/64.f);
      float var = s8v[4+j]*(1.f/64.f) - mu*mu;
      float rv = g2l*(h[j]-mu)*rsqrtf(fmaxf(var,0.f) + 1e-6f) + b2ll;
      int grow = bp*SS + t0 + r;
      R[grow*64 + lane] = rv;
      pr[j] = rv * wfv;
    }
    wred_sum_n<4>(pr);
    if (lane == 0){
#pragma unroll
      for (int j = 0; j < 4; ++j){
        int grow = bp*SS + t0 + w*4 + j;
        pred[grow]  = pr[j] + bfv;
        predr[grow] = pr[j] + bfv;
      }
    }
  }
}

extern "C" void kernel_launch(void* const* d_in, const int* in_sizes, int n_in,
                              void* d_out, int out_size, void* d_ws, size_t ws_size,
                              hipStream_t stream){
  const float* inputs = (const float*)d_in[0];
  const float* Wp  = (const float*)d_in[2];
  const float* bpj = (const float*)d_in[3];
  const float* Wq  = (const float*)d_in[4];  const float* bq  = (const float*)d_in[5];
  const float* Wk  = (const float*)d_in[6];  const float* bk  = (const float*)d_in[7];
  const float* Wv  = (const float*)d_in[8];  const float* bv  = (const float*)d_in[9];
  const float* Wo  = (const float*)d_in[10]; const float* bo  = (const float*)d_in[11];
  const float* g1  = (const float*)d_in[12]; const float* b1l = (const float*)d_in[13];
  const float* W1  = (const float*)d_in[14]; const float* b1  = (const float*)d_in[15];
  const float* W2  = (const float*)d_in[16]; const float* b2  = (const float*)d_in[17];
  const float* g2  = (const float*)d_in[18]; const float* b2l = (const float*)d_in[19];
  const float* Wf  = (const float*)d_in[20]; const float* bf  = (const float*)d_in[21];

  float* outp = (float*)d_out;
  unsigned* ws = (unsigned*)d_ws;
  unsigned* Kp    = ws;                 // 409600 u32
  unsigned* Vp    = ws + 409600;        // 409600 u32
  unsigned* flags = ws + 819200;        // 800 u32 (poison 0xAA.. != MAGIC)

  float* pred  = outp + OFF_PRED;
  float* predr = outp + OFF_PREDR;
  float* Kc    = outp + OFF_K;
  float* Vc    = outp + OFF_V;
  float* Rr    = outp + OFF_R;
  float* attn  = outp + OFF_ATTN;

  k_all<<<dim3(NBP, 10), 256, 0, stream>>>(inputs, Wp, bpj, Wq, bq, Wk, bk,
                                           Wv, bv, Wo, bo, g1, b1l, W1, b1,
                                           W2, b2, g2, b2l, Wf, bf,
                                           Kp, Vp, flags, Kc, Vc,
                                           attn, Rr, pred, predr);
}